// Round 2
// baseline (521.030 us; speedup 1.0000x reference)
//
#include <hip/hip_runtime.h>

#define WD 1024
#define HT 1024

__device__ __forceinline__ int refl(int g, int n) {
    g = (g < 0) ? -g : g;
    return (g >= n) ? (2 * n - 2 - g) : g;
}

__device__ __forceinline__ float4 conv5(float4 a, float4 b, float4 c, float4 d, float4 e) {
    // K0*(a+e) + K1*(b+d) + K2*c, componentwise
    float4 o;
    o.x = 0.0625f * (a.x + e.x) + 0.25f * (b.x + d.x) + 0.375f * c.x;
    o.y = 0.0625f * (a.y + e.y) + 0.25f * (b.y + d.y) + 0.375f * c.y;
    o.z = 0.0625f * (a.z + e.z) + 0.25f * (b.z + d.z) + 0.375f * c.z;
    o.w = 0.0625f * (a.w + e.w) + 0.25f * (b.w + d.w) + 0.375f * c.w;
    return o;
}

__device__ __forceinline__ float4 sub4(float4 a, float4 b) {
    return make_float4(a.x - b.x, a.y - b.y, a.z - b.z, a.w - b.w);
}

// ================= Kernel 1: scales 0 (d=1) + 1 (d=2), tile 64x64 ============
// A: 76 rows x 80 cols. x-origin bx-8 (aligned; need [-6,70)), y-origin by-6.
// B: reused: h0 out 76x72 (x-origin -4), then h1 out 72x64 (x-origin 0).
__global__ __launch_bounds__(256) void starlet01(
    const float* __restrict__ in, long in_bs,
    float* __restrict__ det0, float* __restrict__ det1, long ob,
    float* __restrict__ c2, long c2_bs)
{
    __shared__ float A[76 * 80];
    __shared__ float B[76 * 72];
    const int tid = threadIdx.x;
    const int bx = blockIdx.x * 64, by = blockIdx.y * 64;
    const int b = blockIdx.z;
    const float* __restrict__ inp = in + (long)b * in_bs;
    const float K0 = 0.0625f, K1 = 0.25f, K2 = 0.375f;

    const bool interior = (bx >= 8) && (bx + 72 <= WD) && (by >= 6) && (by + 70 <= HT);

    if (interior) {
        const float4* __restrict__ src =
            (const float4*)(inp + (long)(by - 6) * WD + (bx - 8));
        float4* __restrict__ dst = (float4*)A;
        #pragma unroll 2
        for (int i = tid; i < 76 * 20; i += 256) {
            int r = i / 20, c = i - r * 20;
            dst[i] = src[(long)r * (WD / 4) + c];
        }
    } else {
        for (int i = tid; i < 76 * 80; i += 256) {
            int r = i / 80, c = i - r * 80;
            int gy = refl(by - 6 + r, HT);
            int gx = refl(bx - 8 + c, WD);
            A[i] = inp[(long)gy * WD + gx];
        }
    }
    __syncthreads();

    // h0 (d=1): B[r][c] over 76 rows x 72 cols (18 float4 groups).
    for (int i = tid; i < 76 * 18; i += 256) {
        int r = i / 18, cg = i - r * 18;
        int c = cg * 4;
        const float* a = &A[r * 80 + c];
        float4 f0 = *(const float4*)(a);
        float4 f1 = *(const float4*)(a + 4);
        float4 f2 = *(const float4*)(a + 8);
        float4 o;
        o.x = K0 * (f0.z + f1.z) + K1 * (f0.w + f1.y) + K2 * f1.x;
        o.y = K0 * (f0.w + f1.w) + K1 * (f1.x + f1.z) + K2 * f1.y;
        o.z = K0 * (f1.x + f2.x) + K1 * (f1.y + f1.w) + K2 * f1.z;
        o.w = K0 * (f1.y + f2.y) + K1 * (f1.z + f2.x) + K2 * f1.w;
        *(float4*)&B[r * 72 + c] = o;
    }
    __syncthreads();

    // v0: coarse1 over 72x72 (x,y-origin -4). det0 on central 64x64. c1 -> A in place.
    for (int i = tid; i < 72 * 18; i += 256) {
        int r = i / 18, cg = i - r * 18;
        int c = cg * 4;
        float4 b0 = *(const float4*)&B[(r + 0) * 72 + c];
        float4 b1 = *(const float4*)&B[(r + 1) * 72 + c];
        float4 b2 = *(const float4*)&B[(r + 2) * 72 + c];
        float4 b3 = *(const float4*)&B[(r + 3) * 72 + c];
        float4 b4 = *(const float4*)&B[(r + 4) * 72 + c];
        float4 c1v = conv5(b0, b1, b2, b3, b4);
        float4* aslot = (float4*)&A[(r + 2) * 80 + c + 4];
        float4 xv = *aslot;
        if (r >= 4 && r < 68 && c >= 4 && c < 68) {
            int gy = by + r - 4, gx = bx + c - 4;
            *(float4*)&det0[(long)b * ob + (long)gy * WD + gx] = sub4(xv, c1v);
        }
        *aslot = c1v;
    }
    __syncthreads();

    // h1 (d=2): B2 (stride 64) over rows 72 (y-origin -4) x cols 64 (x-origin 0).
    for (int i = tid; i < 72 * 16; i += 256) {
        int r = i / 16, cg = i - r * 16;
        int c = cg * 4;
        const float* a = &A[(r + 2) * 80 + c + 4];
        float4 f0 = *(const float4*)(a);
        float4 f1 = *(const float4*)(a + 4);
        float4 f2 = *(const float4*)(a + 8);
        float4 o;
        o.x = K0 * (f0.x + f2.x) + K1 * (f0.z + f1.z) + K2 * f1.x;
        o.y = K0 * (f0.y + f2.y) + K1 * (f0.w + f1.w) + K2 * f1.y;
        o.z = K0 * (f0.z + f2.z) + K1 * (f1.x + f2.x) + K2 * f1.z;
        o.w = K0 * (f0.w + f2.w) + K1 * (f1.y + f2.y) + K2 * f1.w;
        *(float4*)&B[r * 64 + c] = o;
    }
    __syncthreads();

    // v1: coarse2 + det1 on 64x64; store det1, c2.
    for (int i = tid; i < 64 * 16; i += 256) {
        int r = i / 16, cg = i - r * 16;
        int c = cg * 4;
        float4 b0 = *(const float4*)&B[(r + 0) * 64 + c];
        float4 b2 = *(const float4*)&B[(r + 2) * 64 + c];
        float4 b4 = *(const float4*)&B[(r + 4) * 64 + c];
        float4 b6 = *(const float4*)&B[(r + 6) * 64 + c];
        float4 b8 = *(const float4*)&B[(r + 8) * 64 + c];
        float4 cv = conv5(b0, b2, b4, b6, b8);
        float4 c1v = *(const float4*)&A[(r + 6) * 80 + c + 8];
        long gidx = (long)(by + r) * WD + (bx + c);
        *(float4*)&det1[(long)b * ob + gidx] = sub4(c1v, cv);
        *(float4*)&c2[(long)b * c2_bs + gidx] = cv;
    }
}

// ================= Kernel 2: scales 2 (d=4) + 3 (d=8), tile 64x32 ============
// A: 80 rows x 112 cols. x-origin bx-24, y-origin by-24.
// B: h2 out 80x96 (x-origin -16, y-origin -24), then h3 out 64x64 (x-origin 0, y-origin -16).
__global__ __launch_bounds__(256) void starlet23(
    const float* __restrict__ in, long in_bs,
    float* __restrict__ det2, float* __restrict__ det3, long ob,
    float* __restrict__ c4, long c4_bs)
{
    __shared__ float A[80 * 112];
    __shared__ float B[80 * 96];
    const int tid = threadIdx.x;
    const int bx = blockIdx.x * 64, by = blockIdx.y * 32;
    const int b = blockIdx.z;
    const float* __restrict__ inp = in + (long)b * in_bs;

    const bool interior = (bx >= 24) && (bx + 88 <= WD) && (by >= 24) && (by + 56 <= HT);

    if (interior) {
        const float4* __restrict__ src =
            (const float4*)(inp + (long)(by - 24) * WD + (bx - 24));
        float4* __restrict__ dst = (float4*)A;
        #pragma unroll 2
        for (int i = tid; i < 80 * 28; i += 256) {
            int r = i / 28, c = i - r * 28;
            dst[i] = src[(long)r * (WD / 4) + c];
        }
    } else {
        for (int i = tid; i < 80 * 112; i += 256) {
            int r = i / 112, c = i - r * 112;
            int gy = refl(by - 24 + r, HT);
            int gx = refl(bx - 24 + c, WD);
            A[i] = inp[(long)gy * WD + gx];
        }
    }
    __syncthreads();

    // h2 (d=4): taps are aligned float4 groups (stride 4 == vector width).
    // B[r][c] over 80 rows x 96 cols: reads A cols c+{0,4,8,12,16}, row r.
    for (int i = tid; i < 80 * 24; i += 256) {
        int r = i / 24, cg = i - r * 24;
        int c = cg * 4;
        const float* a = &A[r * 112 + c];
        float4 g0 = *(const float4*)(a);
        float4 g1 = *(const float4*)(a + 4);
        float4 g2 = *(const float4*)(a + 8);
        float4 g3 = *(const float4*)(a + 12);
        float4 g4 = *(const float4*)(a + 16);
        *(float4*)&B[r * 96 + c] = conv5(g0, g1, g2, g3, g4);
    }
    __syncthreads();

    // v2: coarse3 over 96 cols x 64 rows (x-origin -16, y-origin -16).
    // det2 on central 64x32 (c in [16,80), r in [16,48)). c3 -> A in place.
    for (int i = tid; i < 64 * 24; i += 256) {
        int r = i / 24, cg = i - r * 24;
        int c = cg * 4;
        float4 b0 = *(const float4*)&B[(r + 0) * 96 + c];
        float4 b1 = *(const float4*)&B[(r + 4) * 96 + c];
        float4 b2 = *(const float4*)&B[(r + 8) * 96 + c];
        float4 b3 = *(const float4*)&B[(r + 12) * 96 + c];
        float4 b4 = *(const float4*)&B[(r + 16) * 96 + c];
        float4 c3v = conv5(b0, b1, b2, b3, b4);
        float4* aslot = (float4*)&A[(r + 8) * 112 + c + 8];
        float4 xv = *aslot;
        if (r >= 16 && r < 48 && c >= 16 && c < 80) {
            int gy = by + r - 16, gx = bx + c - 16;
            *(float4*)&det2[(long)b * ob + (long)gy * WD + gx] = sub4(xv, c3v);
        }
        *aslot = c3v;
    }
    __syncthreads();

    // h3 (d=8): B2 (stride 64) over rows 64 (y-origin -16) x cols 64 (x-origin 0).
    // reads A(c3) cols c+{8,16,24,32,40}, row r+8. Taps aligned (8 % 4 == 0).
    for (int i = tid; i < 64 * 16; i += 256) {
        int r = i / 16, cg = i - r * 16;
        int c = cg * 4;
        const float* a = &A[(r + 8) * 112 + c + 8];
        float4 g0 = *(const float4*)(a);
        float4 g1 = *(const float4*)(a + 8);
        float4 g2 = *(const float4*)(a + 16);
        float4 g3 = *(const float4*)(a + 24);
        float4 g4 = *(const float4*)(a + 32);
        *(float4*)&B[r * 64 + c] = conv5(g0, g1, g2, g3, g4);
    }
    __syncthreads();

    // v3: coarse4 + det3 on 64x32; taps B2 rows r+{0,8,16,24,32}.
    for (int i = tid; i < 32 * 16; i += 256) {
        int r = i / 16, cg = i - r * 16;
        int c = cg * 4;
        float4 b0 = *(const float4*)&B[(r + 0) * 64 + c];
        float4 b1 = *(const float4*)&B[(r + 8) * 64 + c];
        float4 b2 = *(const float4*)&B[(r + 16) * 64 + c];
        float4 b3 = *(const float4*)&B[(r + 24) * 64 + c];
        float4 b4 = *(const float4*)&B[(r + 32) * 64 + c];
        float4 c4v = conv5(b0, b1, b2, b3, b4);
        float4 c3v = *(const float4*)&A[(r + 24) * 112 + c + 24];
        long gidx = (long)(by + r) * WD + (bx + c);
        *(float4*)&det3[(long)b * ob + gidx] = sub4(c3v, c4v);
        *(float4*)&c4[(long)b * c4_bs + gidx] = c4v;
    }
}

extern "C" void kernel_launch(void* const* d_in, const int* in_sizes, int n_in,
                              void* d_out, int out_size, void* d_ws, size_t ws_size,
                              hipStream_t stream) {
    const float* x = (const float*)d_in[0];
    float* out = (float*)d_out;
    float* ws = (float*)d_ws;  // holds coarse2: 16 * 1024 * 1024 floats = 64 MiB

    const long HW = 1024L * 1024L;
    const long OB = 5 * HW;
    dim3 blk(256);

    // scales 0,1: x -> det(ch0), det(ch1), coarse2 -> ws
    starlet01<<<dim3(16, 16, 16), blk, 0, stream>>>(
        x, HW, out + 0 * HW, out + 1 * HW, OB, ws, HW);
    // scales 2,3: ws -> det(ch2), det(ch3), coarse4 -> out ch4
    starlet23<<<dim3(16, 32, 16), blk, 0, stream>>>(
        ws, HW, out + 2 * HW, out + 3 * HW, OB, out + 4 * HW, OB);
}